// Round 18
// baseline (38.468 us; speedup 1.0000x reference)
//
#include <hip/hip_runtime.h>

// PSROI pooling: fsam (N=8, C=245, H=80, W=80) f32, box (R=8192, 5) f32
// out (R, 245) f32. out[r, c] = mean over fsam[b, c, hs:he, ws:we].
//
// ARITHMETIC (frozen since R10, DO NOT TOUCH): bin = roi * fl32(1/7)
// (reciprocal multiply, 0x3E124925) and edges = SEPARATELY-rounded
// g*bin + off (asm barriers). Matches ref (absmax <= 0.016 << 0.0725).
//
// R18: SINGLE kernel. R17's 8-block bucket kernel (~4-5us, serial before
// fused) + graph launch gap (~2us) removed: each fused block scans the
// box b-column itself (16 scattered 4B loads/thread, issued with the
// plane loads so they hide under the SAT build; the 160KB b-column is
// L2-resident per XCD since all 245 blocks of an image share it) into a
// register match-mask; pool walks mask bits. Per-ROI pool work is a
// strict subset of R17's (no bucket-index load). No workspace, no
// inter-kernel dependency. SAT structure and all arithmetic identical to
// R17 -> bit-identical output.

#define N_ 8
#define C_ 245
#define H_ 80
#define W_ 80
#define R_ 8192
#define P_ 7
#define SROW 84                    // row stride in floats (21 float4)

// XLA-style separately-rounded a*b + c in f32; barriers forbid contraction.
__device__ __forceinline__ float sep_ma(float a, float b, float c) {
    float p = a * b;                 // v_mul_f32, IEEE RN
    asm volatile("" : "+v"(p));      // contraction barrier
    float s = p + c;                 // v_add_f32, IEEE RN
    asm volatile("" : "+v"(s));
    return s;
}

__device__ __forceinline__ float4 f4_add(float4 a, float4 b) {
    return make_float4(a.x + b.x, a.y + b.y, a.z + b.z, a.w + b.w);
}

// ---- fused: SAT-in-LDS + self-bucket + pool, 512 threads ----
__global__ __launch_bounds__(512) void fused_kernel(
    const float* __restrict__ fsam,
    const float* __restrict__ box,
    float* __restrict__ out)
{
    __shared__ float S[H_ * SROW];         // 26880 B, rows 16B-aligned
    int id  = blockIdx.x;                  // 0..1959
    int b   = id & 7;                      // image (XCD swizzle: XCD = b)
    int c   = id >> 3;                     // channel 0..244
    int tid = threadIdx.x;

    const float* plane = fsam + ((size_t)b * C_ + c) * (H_ * W_);

    // ---- load: 1600 float4, coalesced global -> b128 LDS ----
    for (int i = tid; i < 1600; i += 512) {
        int row = (int)((unsigned)i / 20u);
        int c4  = i - row * 20;
        float4 v = ((const float4*)plane)[i];
        ((float4*)S)[row * 21 + c4] = v;
    }

    // ---- self-bucket: scan b-column into a register mask (overlaps SAT
    //      build; independent of the LDS barriers) ----
    unsigned bmask = 0u;
    #pragma unroll
    for (int k = 0; k < 16; ++k) {
        int r = tid + (k << 9);
        if ((int)box[(size_t)r * 5] == b) bmask |= 1u << k;
    }
    __syncthreads();

    // ---- horizontal scan: 80 rows x 4 chunks of 20, in registers ----
    if (tid < 320) {
        int row = tid >> 2, q = tid & 3;   // chunk q covers cols q*20..q*20+19
        float4* base = (float4*)S + row * 21 + q * 5;
        float v[20];
        #pragma unroll
        for (int k = 0; k < 5; ++k) {
            float4 t = base[k];
            v[4*k+0] = t.x; v[4*k+1] = t.y; v[4*k+2] = t.z; v[4*k+3] = t.w;
        }
        float run = 0.0f;
        #pragma unroll
        for (int j = 0; j < 20; ++j) { run += v[j]; v[j] = run; }
        // segmented inclusive scan of chunk totals across 4 lanes (quad)
        float incl = run;
        #pragma unroll
        for (int d = 1; d < 4; d <<= 1) {
            float u = __shfl_up(incl, d, 4);
            if (q >= d) incl += u;
        }
        float off = incl - run;            // exclusive prefix for this chunk
        #pragma unroll
        for (int j = 0; j < 20; ++j) v[j] += off;
        #pragma unroll
        for (int k = 0; k < 5; ++k)
            base[k] = make_float4(v[4*k+0], v[4*k+1], v[4*k+2], v[4*k+3]);
    }
    __syncthreads();

    // ---- vertical scan: 20 col-groups x 16 chunks of 5 rows ----
    if (tid < 320) {
        int cg = tid >> 4;                 // 0..19 (cols cg*4..cg*4+3)
        int ch = tid & 15;                 // 0..15 (rows ch*5..ch*5+4)
        float4* col = (float4*)S + cg;
        float4 v[5];
        float4 run = make_float4(0.f, 0.f, 0.f, 0.f);
        #pragma unroll
        for (int j = 0; j < 5; ++j) {
            run = f4_add(run, col[(ch * 5 + j) * 21]);
            v[j] = run;
        }
        // segmented inclusive scan of chunk totals across 16 lanes
        float4 incl = run;
        #pragma unroll
        for (int d = 1; d < 16; d <<= 1) {
            float4 u;
            u.x = __shfl_up(incl.x, d, 16);
            u.y = __shfl_up(incl.y, d, 16);
            u.z = __shfl_up(incl.z, d, 16);
            u.w = __shfl_up(incl.w, d, 16);
            if (ch >= d) incl = f4_add(incl, u);
        }
        float4 off = make_float4(incl.x - run.x, incl.y - run.y,
                                 incl.z - run.z, incl.w - run.w);
        #pragma unroll
        for (int j = 0; j < 5; ++j)
            col[(ch * 5 + j) * 21] = f4_add(v[j], off);
    }
    __syncthreads();

    // ---- pool: walk the match mask (order-independent per-ROI work) ----
    int ph = (c / P_) % P_;                // block-uniform
    int pw = c % P_;

    while (bmask) {
        int k = __ffs(bmask) - 1;
        bmask &= bmask - 1u;
        int r = tid + (k << 9);
        const float* bx = box + (size_t)r * 5;

        // ---- R10-frozen edge arithmetic ----
        float x1 = rintf(bx[1]);
        float y1 = rintf(bx[2]);
        float x2 = rintf(bx[3] + 1.0f);
        float y2 = rintf(bx[4] + 1.0f);

        float roi_w = fmaxf(x2 - x1, 0.1f);
        float roi_h = fmaxf(y2 - y1, 0.1f);

        const float RCP7 = __uint_as_float(0x3E124925u); // fl32(1/7)
        float bin_w = roi_w * RCP7;
        float bin_h = roi_h * RCP7;
        asm volatile("" : "+v"(bin_w), "+v"(bin_h));

        float hs_f = floorf(sep_ma((float)ph,       bin_h, y1));
        float he_f = ceilf (sep_ma((float)(ph + 1), bin_h, y1));
        float ws_f = floorf(sep_ma((float)pw,       bin_w, x1));
        float we_f = ceilf (sep_ma((float)(pw + 1), bin_w, x1));

        int hs = (int)fminf(fmaxf(hs_f, 0.0f), 80.0f);
        int he = (int)fminf(fmaxf(he_f, 0.0f), 80.0f);
        int ws = (int)fminf(fmaxf(ws_f, 0.0f), 80.0f);
        int we = (int)fminf(fmaxf(we_f, 0.0f), 80.0f);

        // SAT taps with implicit zero row/col (clamp + select)
        int i1 = he > 0 ? he - 1 : 0, i0 = hs > 0 ? hs - 1 : 0;
        int j1 = we > 0 ? we - 1 : 0, j0 = ws > 0 ? ws - 1 : 0;
        float v11 = S[i1 * SROW + j1];
        float v01 = S[i0 * SROW + j1];
        float v10 = S[i1 * SROW + j0];
        float v00 = S[i0 * SROW + j0];
        float t11 = (he > 0 && we > 0) ? v11 : 0.0f;
        float t01 = (hs > 0 && we > 0) ? v01 : 0.0f;
        float t10 = (he > 0 && ws > 0) ? v10 : 0.0f;
        float t00 = (hs > 0 && ws > 0) ? v00 : 0.0f;
        float bin_sum = ((t11 - t01) - t10) + t00;   // ref op order

        int area = (he - hs) * (we - ws);
        out[(size_t)r * C_ + c] = (area > 0) ? bin_sum / (float)area : 0.0f;
    }
}

extern "C" void kernel_launch(void* const* d_in, const int* in_sizes, int n_in,
                              void* d_out, int out_size, void* d_ws, size_t ws_size,
                              hipStream_t stream) {
    const float* fsam = (const float*)d_in[0];
    const float* box  = (const float*)d_in[1];
    float* out = (float*)d_out;

    fused_kernel<<<N_ * C_, 512, 0, stream>>>(fsam, box, out);
}